// Round 7
// baseline (280.269 us; speedup 1.0000x reference)
//
#include <hip/hip_runtime.h>
#include <math.h>

#define HW 28
#define PR 30            // padded rows
#define PC 32            // padded col stride
#define PPAD (PR * PC)   // 960 floats per padded plane

// ws float offsets
#define OFF_H1P 0
#define OFF_H2P 491520
#define OFF_H3  983040
#define OFF_W1T 1384448   // 16384 floats: [256 ci][64 co]
#define OFF_W2T 1400832   // 36864 floats: [576 r][64 co]  (r = ci*9+tap)
#define OFF_W3T 1437696   // 16384 floats: [64 ci][256 co]

// 4px x 3kw taps for one co
__device__ __forceinline__ void tap3(const float4 a, const float2 b,
                                     const float w0, const float w1, const float w2,
                                     float4& acc) {
    acc.x += fabsf(a.x - w0) + fabsf(a.y - w1) + fabsf(a.z - w2);
    acc.y += fabsf(a.y - w0) + fabsf(a.z - w1) + fabsf(a.w - w2);
    acc.z += fabsf(a.z - w0) + fabsf(a.w - w1) + fabsf(b.x - w2);
    acc.w += fabsf(a.w - w0) + fabsf(b.x - w1) + fabsf(b.y - w2);
}

// ---------------- K0: zero h1p+h2p AND transpose weights ----------------
// blocks 0..959: zero 16B each thread (3.93MB). blocks 960..1231: transpose 69632 elems.
__global__ __launch_bounds__(256) void k0_setup(float4* __restrict__ zbuf,
                                                const float* __restrict__ w1,
                                                const float* __restrict__ w2,
                                                const float* __restrict__ w3,
                                                float* __restrict__ w1t,
                                                float* __restrict__ w2t,
                                                float* __restrict__ w3t) {
    const int b = blockIdx.x;
    if (b < 960) {
        zbuf[b * 256 + threadIdx.x] = make_float4(0.f, 0.f, 0.f, 0.f);
        return;
    }
    int t = (b - 960) * 256 + threadIdx.x;
    if (t < 16384) {                       // w1t[ci*64+co] = w1[co*256+ci]
        int ci = t >> 6, co = t & 63;
        w1t[t] = w1[co * 256 + ci];
    } else if (t < 53248) {                // w2t[r*64+co] = w2[co*576+r]
        int r = t - 16384;
        int rr = r >> 6, co = r & 63;
        w2t[r] = w2[co * 576 + rr];
    } else if (t < 69632) {                // w3t[ci*256+co] = w3[co*64+ci]
        int r = t - 53248;
        int ci = r >> 8, co = r & 255;
        w3t[r] = w3[co * 64 + ci];
    }
}

// ---------------- K1: 1x1 adder 256->64, out = PADDED h1p ----------------
// grid (112, 4), block 448 = 4 cog x 14 pxg x 8 cic. Thread: 4px x 4co x 32ci.
// Weights read directly from w1t (uniform across pxg -> L1 broadcast).
__global__ __launch_bounds__(448, 4) void k1_adder1x1(const float* __restrict__ x,
                                                      const float* __restrict__ w1t,
                                                      float* __restrict__ h1p) {
    __shared__ float4 pl[1792];       // [cic8][pxg14][cog4][j4]
    const int tid    = threadIdx.x;
    const int cog    = tid & 3;
    const int pxg    = (tid >> 2) % 14;
    const int cic    = tid / 56;                 // 0..7
    const int n      = blockIdx.x / 14;
    const int p0     = (blockIdx.x % 14) * 56 + pxg * 4;   // 0..780
    const int cobase = blockIdx.y * 16;

    float4 acc0 = {0,0,0,0}, acc1 = acc0, acc2 = acc0, acc3 = acc0;
    const float* xp = x + ((size_t)n * 256 + cic * 32) * 784 + p0;
    const float* wp = w1t + (size_t)(cic * 32) * 64 + cobase + cog * 4;
    #pragma unroll 8
    for (int i = 0; i < 32; ++i) {
        float4 u = *(const float4*)(xp + (size_t)i * 784);
        float4 w = *(const float4*)(wp + i * 64);
        acc0.x += fabsf(u.x - w.x); acc0.y += fabsf(u.y - w.x); acc0.z += fabsf(u.z - w.x); acc0.w += fabsf(u.w - w.x);
        acc1.x += fabsf(u.x - w.y); acc1.y += fabsf(u.y - w.y); acc1.z += fabsf(u.z - w.y); acc1.w += fabsf(u.w - w.y);
        acc2.x += fabsf(u.x - w.z); acc2.y += fabsf(u.y - w.z); acc2.z += fabsf(u.z - w.z); acc2.w += fabsf(u.w - w.z);
        acc3.x += fabsf(u.x - w.w); acc3.y += fabsf(u.y - w.w); acc3.z += fabsf(u.z - w.w); acc3.w += fabsf(u.w - w.w);
    }
    const int pbase = pxg * 16 + cog * 4;
    pl[cic * 224 + pbase + 0] = acc0;
    pl[cic * 224 + pbase + 1] = acc1;
    pl[cic * 224 + pbase + 2] = acc2;
    pl[cic * 224 + pbase + 3] = acc3;
    __syncthreads();

    if (tid < 224) {
        const int j = cic;   // 0..3
        float4 s = pl[pbase + j];
        #pragma unroll
        for (int c = 1; c < 8; ++c) {
            float4 t = pl[c * 224 + pbase + j];
            s.x += t.x; s.y += t.y; s.z += t.z; s.w += t.w;
        }
        const int co = cobase + cog * 4 + j;
        const int y = p0 / 28, xx = p0 % 28;
        float* op = h1p + ((size_t)(n * 64 + co) * PR + y + 1) * PC + xx + 1;
        op[0] = -s.x; op[1] = -s.y; op[2] = -s.z; op[3] = -s.w;
    }
}

// ---------------- K2: depthwise 3x3 (PEG) + BN1 + ReLU, padded->padded ----------------
__global__ __launch_bounds__(256) void k2_peg_bn_relu(const float* __restrict__ h1p,
                                                      const float* __restrict__ wp,
                                                      const float* __restrict__ g1,
                                                      const float* __restrict__ b1,
                                                      const float* __restrict__ m1,
                                                      const float* __restrict__ v1,
                                                      float* __restrict__ h2p) {
    const int t   = blockIdx.x * 256 + threadIdx.x;   // < 8*64*196
    const int pxq = t % 196;
    const int c   = (t / 196) & 63;
    const int n   = t / (196 * 64);
    const int p0  = pxq * 4;
    const int y   = p0 / 28, xx = p0 % 28;

    const float* base = h1p + ((size_t)(n * 64 + c) * PR + y) * PC + xx;
    const float* wc   = wp + c * 9;
    float4 acc = {0,0,0,0};
    #pragma unroll
    for (int kh = 0; kh < 3; ++kh) {
        float4 a = *(const float4*)(base + kh * PC);
        float2 b = *(const float2*)(base + kh * PC + 4);
        tap3(a, b, wc[kh * 3 + 0], wc[kh * 3 + 1], wc[kh * 3 + 2], acc);
    }
    float inv = g1[c] * rsqrtf(v1[c] + 1e-5f);
    float bb  = b1[c] - m1[c] * inv;
    float* op = h2p + ((size_t)(n * 64 + c) * PR + y + 1) * PC + xx + 1;
    op[0] = fmaxf(-acc.x * inv + bb, 0.f);
    op[1] = fmaxf(-acc.y * inv + bb, 0.f);
    op[2] = fmaxf(-acc.z * inv + bb, 0.f);
    op[3] = fmaxf(-acc.w * inv + bb, 0.f);
}

// ---------------- K3: 3x3 adder 64->64 + BN2 + ReLU ----------------
// grid (14, 4, 8), block 448 = 4 cog x 14 pxg(2 rows x 7) x 8 cic.
// W staged in LDS from pre-transposed w2t (shift-only addressing);
// x rows hand-prefetched (double-buffered) to hide global latency.
__global__ __launch_bounds__(448, 4) void k3_adder3x3_bn_relu(const float* __restrict__ h2p,
                                                              const float* __restrict__ w2t,
                                                              const float* __restrict__ g2,
                                                              const float* __restrict__ b2,
                                                              const float* __restrict__ m2,
                                                              const float* __restrict__ v2,
                                                              float* __restrict__ h3) {
    __shared__ float  ws[9216];       // [r=ci*9+tap][16 co]
    __shared__ float4 pl[1792];       // [cic8][pxg14][cog4][j4]
    const int tid    = threadIdx.x;
    const int cog    = tid & 3;
    const int pxg    = (tid >> 2) % 14;
    const int cic    = tid / 56;                  // 0..7
    const int y0     = blockIdx.x * 2;
    const int cobase = blockIdx.y * 16;
    const int n      = blockIdx.z;
    const int yl     = pxg / 7;                   // 0..1
    const int xx0    = (pxg % 7) * 4;             // 0..24
    const int Y      = y0 + yl;                   // output row

    #pragma unroll
    for (int k = 0; k < 21; ++k) {
        int idx = tid + k * 448;
        if (idx < 9216) ws[idx] = w2t[(size_t)(idx >> 4) * 64 + cobase + (idx & 15)];
    }
    __syncthreads();

    const float* xb = h2p + (((size_t)(n * 64 + cic * 8)) * PR + Y) * PC + xx0;
    float4 acc0 = {0,0,0,0}, acc1 = acc0, acc2 = acc0, acc3 = acc0;

    float4 r0 = *(const float4*)(xb);        float2 s0 = *(const float2*)(xb + 4);
    float4 r1 = *(const float4*)(xb + PC);   float2 s1 = *(const float2*)(xb + PC + 4);
    float4 r2 = *(const float4*)(xb + 2*PC); float2 s2 = *(const float2*)(xb + 2*PC + 4);

    #pragma unroll
    for (int i = 0; i < 8; ++i) {
        float4 nr0, nr1, nr2; float2 ns0, ns1, ns2;
        if (i < 7) {
            const float* nx = xb + (size_t)(i + 1) * PPAD;
            nr0 = *(const float4*)(nx);        ns0 = *(const float2*)(nx + 4);
            nr1 = *(const float4*)(nx + PC);   ns1 = *(const float2*)(nx + PC + 4);
            nr2 = *(const float4*)(nx + 2*PC); ns2 = *(const float2*)(nx + 2*PC + 4);
        }
        const float* wr = ws + (cic * 8 + i) * 144 + cog * 4;   // 9 taps * 16
        float4 W0, W1, W2;
        W0 = *(const float4*)(wr);      W1 = *(const float4*)(wr + 16); W2 = *(const float4*)(wr + 32);
        tap3(r0, s0, W0.x, W1.x, W2.x, acc0);
        tap3(r0, s0, W0.y, W1.y, W2.y, acc1);
        tap3(r0, s0, W0.z, W1.z, W2.z, acc2);
        tap3(r0, s0, W0.w, W1.w, W2.w, acc3);
        W0 = *(const float4*)(wr + 48); W1 = *(const float4*)(wr + 64); W2 = *(const float4*)(wr + 80);
        tap3(r1, s1, W0.x, W1.x, W2.x, acc0);
        tap3(r1, s1, W0.y, W1.y, W2.y, acc1);
        tap3(r1, s1, W0.z, W1.z, W2.z, acc2);
        tap3(r1, s1, W0.w, W1.w, W2.w, acc3);
        W0 = *(const float4*)(wr + 96); W1 = *(const float4*)(wr + 112); W2 = *(const float4*)(wr + 128);
        tap3(r2, s2, W0.x, W1.x, W2.x, acc0);
        tap3(r2, s2, W0.y, W1.y, W2.y, acc1);
        tap3(r2, s2, W0.z, W1.z, W2.z, acc2);
        tap3(r2, s2, W0.w, W1.w, W2.w, acc3);
        r0 = nr0; s0 = ns0; r1 = nr1; s1 = ns1; r2 = nr2; s2 = ns2;
    }
    const int pbase = pxg * 16 + cog * 4;
    pl[cic * 224 + pbase + 0] = acc0;
    pl[cic * 224 + pbase + 1] = acc1;
    pl[cic * 224 + pbase + 2] = acc2;
    pl[cic * 224 + pbase + 3] = acc3;
    __syncthreads();

    if (tid < 224) {
        const int j = cic;
        float4 s = pl[pbase + j];
        #pragma unroll
        for (int c = 1; c < 8; ++c) {
            float4 t = pl[c * 224 + pbase + j];
            s.x += t.x; s.y += t.y; s.z += t.z; s.w += t.w;
        }
        const int co = cobase + cog * 4 + j;
        float inv = g2[co] * rsqrtf(v2[co] + 1e-5f);
        float bb  = b2[co] - m2[co] * inv;
        float4 o;
        o.x = fmaxf(-s.x * inv + bb, 0.f);
        o.y = fmaxf(-s.y * inv + bb, 0.f);
        o.z = fmaxf(-s.z * inv + bb, 0.f);
        o.w = fmaxf(-s.w * inv + bb, 0.f);
        *(float4*)(h3 + (size_t)(n * 64 + co) * 784 + Y * 28 + xx0) = o;
    }
}

// ---------------- K6: 1x1 adder 64->256 + BN3 + residual + ReLU ----------------
// grid (112, 8), block 448 = 8 cog x 14 pxg x 4 cic. Thread: 4px x 4co x 16ci.
__global__ __launch_bounds__(448, 4) void k6_adder1x1_bn_res_relu(const float* __restrict__ h3,
                                                                  const float* __restrict__ w3t,
                                                                  const float* __restrict__ x,
                                                                  const float* __restrict__ g3,
                                                                  const float* __restrict__ b3,
                                                                  const float* __restrict__ m3,
                                                                  const float* __restrict__ v3,
                                                                  float* __restrict__ out) {
    __shared__ float4 pl[1792];       // [cic4][pxg14][cog8][j4]
    const int tid    = threadIdx.x;
    const int cog    = tid & 7;
    const int pxg    = (tid >> 3) % 14;
    const int cic    = tid / 112;                 // 0..3
    const int n      = blockIdx.x / 14;
    const int p0     = (blockIdx.x % 14) * 56 + pxg * 4;
    const int cobase = blockIdx.y * 32;

    float4 acc0 = {0,0,0,0}, acc1 = acc0, acc2 = acc0, acc3 = acc0;
    const float* hp = h3 + ((size_t)n * 64 + cic * 16) * 784 + p0;
    const float* wp = w3t + (size_t)(cic * 16) * 256 + cobase + cog * 4;
    #pragma unroll 8
    for (int i = 0; i < 16; ++i) {
        float4 u = *(const float4*)(hp + (size_t)i * 784);
        float4 w = *(const float4*)(wp + i * 256);
        acc0.x += fabsf(u.x - w.x); acc0.y += fabsf(u.y - w.x); acc0.z += fabsf(u.z - w.x); acc0.w += fabsf(u.w - w.x);
        acc1.x += fabsf(u.x - w.y); acc1.y += fabsf(u.y - w.y); acc1.z += fabsf(u.z - w.y); acc1.w += fabsf(u.w - w.y);
        acc2.x += fabsf(u.x - w.z); acc2.y += fabsf(u.y - w.z); acc2.z += fabsf(u.z - w.z); acc2.w += fabsf(u.w - w.z);
        acc3.x += fabsf(u.x - w.w); acc3.y += fabsf(u.y - w.w); acc3.z += fabsf(u.z - w.w); acc3.w += fabsf(u.w - w.w);
    }
    const int pbase = pxg * 32 + cog * 4;
    pl[cic * 448 + pbase + 0] = acc0;
    pl[cic * 448 + pbase + 1] = acc1;
    pl[cic * 448 + pbase + 2] = acc2;
    pl[cic * 448 + pbase + 3] = acc3;
    __syncthreads();

    {
        const int j = cic;
        float4 s = pl[pbase + j];
        #pragma unroll
        for (int c = 1; c < 4; ++c) {
            float4 t = pl[c * 448 + pbase + j];
            s.x += t.x; s.y += t.y; s.z += t.z; s.w += t.w;
        }
        const int co = cobase + cog * 4 + j;
        float inv = g3[co] * rsqrtf(v3[co] + 1e-5f);
        float bb  = b3[co] - m3[co] * inv;
        size_t obase = ((size_t)n * 256 + co) * 784 + p0;
        float4 r = *(const float4*)(x + obase);
        float4 o;
        o.x = fmaxf(-s.x * inv + bb + r.x, 0.f);
        o.y = fmaxf(-s.y * inv + bb + r.y, 0.f);
        o.z = fmaxf(-s.z * inv + bb + r.z, 0.f);
        o.w = fmaxf(-s.w * inv + bb + r.w, 0.f);
        *(float4*)(out + obase) = o;
    }
}

extern "C" void kernel_launch(void* const* d_in, const int* in_sizes, int n_in,
                              void* d_out, int out_size, void* d_ws, size_t ws_size,
                              hipStream_t stream) {
    const float* x  = (const float*)d_in[0];
    const float* w1 = (const float*)d_in[1];
    const float* wp = (const float*)d_in[2];
    const float* w2 = (const float*)d_in[3];
    const float* w3 = (const float*)d_in[4];
    const float* g1 = (const float*)d_in[5];
    const float* b1 = (const float*)d_in[6];
    const float* m1 = (const float*)d_in[7];
    const float* v1 = (const float*)d_in[8];
    const float* g2 = (const float*)d_in[9];
    const float* b2 = (const float*)d_in[10];
    const float* m2 = (const float*)d_in[11];
    const float* v2 = (const float*)d_in[12];
    const float* g3 = (const float*)d_in[13];
    const float* b3 = (const float*)d_in[14];
    const float* m3 = (const float*)d_in[15];
    const float* v3 = (const float*)d_in[16];
    float* out = (float*)d_out;

    float* wsf = (float*)d_ws;
    float* h1p = wsf + OFF_H1P;
    float* h2p = wsf + OFF_H2P;
    float* h3  = wsf + OFF_H3;
    float* w1t = wsf + OFF_W1T;
    float* w2t = wsf + OFF_W2T;
    float* w3t = wsf + OFF_W3T;

    k0_setup<<<dim3(1232), 256, 0, stream>>>((float4*)d_ws, w1, w2, w3, w1t, w2t, w3t);
    k1_adder1x1<<<dim3(112, 4), 448, 0, stream>>>(x, w1t, h1p);
    k2_peg_bn_relu<<<dim3(392), 256, 0, stream>>>(h1p, wp, g1, b1, m1, v1, h2p);
    k3_adder3x3_bn_relu<<<dim3(14, 4, 8), 448, 0, stream>>>(h2p, w2t, g2, b2, m2, v2, h3);
    k6_adder1x1_bn_res_relu<<<dim3(112, 8), 448, 0, stream>>>(h3, w3t, x, g3, b3, m3, v3, out);
}

// Round 8
// 69.933 us; speedup vs baseline: 4.0077x; 4.0077x over previous
//
#include <hip/hip_runtime.h>
#include <math.h>

#define HW 28
#define PR 30            // padded rows
#define PC 32            // padded col stride
#define PPAD (PR * PC)   // 960 floats per padded plane

// ws float offsets
#define OFF_H1P 0
#define OFF_H2P 491520
#define OFF_H3  983040
#define OFF_W1T 1384448   // 16384 floats: [256 ci][64 co]
#define OFF_W2T 1400832   // 36864 floats: [576 r][64 co]  (r = ci*9+tap)
#define OFF_W3T 1437696   // 16384 floats: [64 ci][256 co]

// 4px x 3kw taps for one co
__device__ __forceinline__ void tap3(const float4 a, const float2 b,
                                     const float w0, const float w1, const float w2,
                                     float4& acc) {
    acc.x += fabsf(a.x - w0) + fabsf(a.y - w1) + fabsf(a.z - w2);
    acc.y += fabsf(a.y - w0) + fabsf(a.z - w1) + fabsf(a.w - w2);
    acc.z += fabsf(a.z - w0) + fabsf(a.w - w1) + fabsf(b.x - w2);
    acc.w += fabsf(a.w - w0) + fabsf(b.x - w1) + fabsf(b.y - w2);
}

// ---------------- K0: zero h1p+h2p AND transpose weights ----------------
__global__ __launch_bounds__(256) void k0_setup(float4* __restrict__ zbuf,
                                                const float* __restrict__ w1,
                                                const float* __restrict__ w2,
                                                const float* __restrict__ w3,
                                                float* __restrict__ w1t,
                                                float* __restrict__ w2t,
                                                float* __restrict__ w3t) {
    const int b = blockIdx.x;
    if (b < 960) {
        zbuf[b * 256 + threadIdx.x] = make_float4(0.f, 0.f, 0.f, 0.f);
        return;
    }
    int t = (b - 960) * 256 + threadIdx.x;
    if (t < 16384) {                       // w1t[ci*64+co] = w1[co*256+ci]
        int ci = t >> 6, co = t & 63;
        w1t[t] = w1[co * 256 + ci];
    } else if (t < 53248) {                // w2t[r*64+co] = w2[co*576+r]
        int r = t - 16384;
        int rr = r >> 6, co = r & 63;
        w2t[r] = w2[co * 576 + rr];
    } else if (t < 69632) {                // w3t[ci*256+co] = w3[co*64+ci]
        int r = t - 53248;
        int ci = r >> 8, co = r & 255;
        w3t[r] = w3[co * 64 + ci];
    }
}

// ---------------- K1: 1x1 adder 256->64, out = PADDED h1p ----------------
// grid (224, 4): blockIdx.x = n*28 + pxtile(28px). block 448 = 4cog x 7pxg x 16cic.
// Thread: 4px x 4co x 16ci. LDS: weights [256][20] UNION partials (disjoint phases).
__global__ __launch_bounds__(448) void k1_adder1x1(const float* __restrict__ x,
                                                   const float* __restrict__ w1t,
                                                   float* __restrict__ h1p) {
    __shared__ __align__(16) float smem[7168];   // max(ws 5120, pl 7168 floats) = 28KB
    float*  ws  = smem;            // [ci][20] : 16 co + 4 pad
    float4* pl4 = (float4*)smem;   // [cic16][pxg7][cog4][j4] = 1792
    const int tid    = threadIdx.x;
    const int cog    = tid & 3;
    const int pxg    = (tid >> 2) % 7;
    const int cic    = tid / 28;                 // 0..15
    const int n      = blockIdx.x / 28;
    const int pxtile = blockIdx.x % 28;          // = output row y
    const int px0    = pxtile * 28 + pxg * 4;
    const int cobase = blockIdx.y * 16;

    for (int idx = tid; idx < 4096; idx += 448) {
        int ci = idx >> 4, co = idx & 15;
        ws[ci * 20 + co] = w1t[ci * 64 + cobase + co];
    }
    __syncthreads();

    float4 acc0 = {0,0,0,0}, acc1 = acc0, acc2 = acc0, acc3 = acc0;
    const float* xp = x + ((size_t)n * 256 + cic * 16) * 784 + px0;
    const float* wp = ws + (cic * 16) * 20 + cog * 4;
    #pragma unroll 8
    for (int i = 0; i < 16; ++i) {
        float4 u = *(const float4*)(xp + (size_t)i * 784);
        float4 w = *(const float4*)(wp + i * 20);
        acc0.x += fabsf(u.x - w.x); acc0.y += fabsf(u.y - w.x); acc0.z += fabsf(u.z - w.x); acc0.w += fabsf(u.w - w.x);
        acc1.x += fabsf(u.x - w.y); acc1.y += fabsf(u.y - w.y); acc1.z += fabsf(u.z - w.y); acc1.w += fabsf(u.w - w.y);
        acc2.x += fabsf(u.x - w.z); acc2.y += fabsf(u.y - w.z); acc2.z += fabsf(u.z - w.z); acc2.w += fabsf(u.w - w.z);
        acc3.x += fabsf(u.x - w.w); acc3.y += fabsf(u.y - w.w); acc3.z += fabsf(u.z - w.w); acc3.w += fabsf(u.w - w.w);
    }
    __syncthreads();   // all ws reads done before pl overwrites the union
    const int pbase = pxg * 16 + cog * 4;
    pl4[cic * 112 + pbase + 0] = acc0;
    pl4[cic * 112 + pbase + 1] = acc1;
    pl4[cic * 112 + pbase + 2] = acc2;
    pl4[cic * 112 + pbase + 3] = acc3;
    __syncthreads();

    if (tid < 112) {
        const int rpxg = tid >> 4;
        const int rcog = (tid >> 2) & 3;
        const int j    = tid & 3;
        const int rb   = rpxg * 16 + rcog * 4 + j;
        float4 s = pl4[rb];
        #pragma unroll
        for (int c = 1; c < 16; ++c) {
            float4 t = pl4[c * 112 + rb];
            s.x += t.x; s.y += t.y; s.z += t.z; s.w += t.w;
        }
        const int co = cobase + rcog * 4 + j;
        float* op = h1p + ((size_t)(n * 64 + co) * PR + pxtile + 1) * PC + rpxg * 4 + 1;
        op[0] = -s.x; op[1] = -s.y; op[2] = -s.z; op[3] = -s.w;
    }
}

// ---------------- K2: depthwise 3x3 (PEG) + BN1 + ReLU, padded->padded ----------------
__global__ __launch_bounds__(256) void k2_peg_bn_relu(const float* __restrict__ h1p,
                                                      const float* __restrict__ wp,
                                                      const float* __restrict__ g1,
                                                      const float* __restrict__ b1,
                                                      const float* __restrict__ m1,
                                                      const float* __restrict__ v1,
                                                      float* __restrict__ h2p) {
    const int t   = blockIdx.x * 256 + threadIdx.x;   // < 8*64*196
    const int pxq = t % 196;
    const int c   = (t / 196) & 63;
    const int n   = t / (196 * 64);
    const int p0  = pxq * 4;
    const int y   = p0 / 28, xx = p0 % 28;

    const float* base = h1p + ((size_t)(n * 64 + c) * PR + y) * PC + xx;
    const float* wc   = wp + c * 9;
    float4 acc = {0,0,0,0};
    #pragma unroll
    for (int kh = 0; kh < 3; ++kh) {
        float4 a = *(const float4*)(base + kh * PC);
        float2 b = *(const float2*)(base + kh * PC + 4);
        tap3(a, b, wc[kh * 3 + 0], wc[kh * 3 + 1], wc[kh * 3 + 2], acc);
    }
    float inv = g1[c] * rsqrtf(v1[c] + 1e-5f);
    float bb  = b1[c] - m1[c] * inv;
    float* op = h2p + ((size_t)(n * 64 + c) * PR + y + 1) * PC + xx + 1;
    op[0] = fmaxf(-acc.x * inv + bb, 0.f);
    op[1] = fmaxf(-acc.y * inv + bb, 0.f);
    op[2] = fmaxf(-acc.z * inv + bb, 0.f);
    op[3] = fmaxf(-acc.w * inv + bb, 0.f);
}

// ---------------- K3: 3x3 adder 64->64 + BN2 + ReLU ----------------
// grid (28, 4, 8): one output row per block. block 448 = 4cog x 7pxg x 16cic.
// Thread: 4px x 4co x 4ci x 9taps. W in LDS (shift-only staging from w2t),
// LDS weights UNION partials (36KB total -> 4 blocks/CU possible).
__global__ __launch_bounds__(448) void k3_adder3x3_bn_relu(const float* __restrict__ h2p,
                                                           const float* __restrict__ w2t,
                                                           const float* __restrict__ g2,
                                                           const float* __restrict__ b2,
                                                           const float* __restrict__ m2,
                                                           const float* __restrict__ v2,
                                                           float* __restrict__ h3) {
    __shared__ __align__(16) float smem[9216];   // ws [576 r][16 co] (36KB) union pl (28KB)
    float*  ws  = smem;
    float4* pl4 = (float4*)smem;   // [cic16][pxg7][cog4][j4] = 1792
    const int tid    = threadIdx.x;
    const int cog    = tid & 3;
    const int pxg    = (tid >> 2) % 7;
    const int cic    = tid / 28;                  // 0..15
    const int Y      = blockIdx.x;                // output row 0..27
    const int cobase = blockIdx.y * 16;
    const int n      = blockIdx.z;
    const int xx0    = pxg * 4;

    #pragma unroll
    for (int k = 0; k < 21; ++k) {
        int idx = tid + k * 448;
        if (idx < 9216) ws[idx] = w2t[(size_t)(idx >> 4) * 64 + cobase + (idx & 15)];
    }
    __syncthreads();

    float4 acc0 = {0,0,0,0}, acc1 = acc0, acc2 = acc0, acc3 = acc0;
    #pragma unroll 2
    for (int i = 0; i < 4; ++i) {
        const int ci = cic * 4 + i;
        const float* rp = h2p + (((size_t)(n * 64 + ci)) * PR + Y) * PC + xx0;
        const float* wr = ws + ci * 144 + cog * 4;   // 9 taps * 16
        #pragma unroll
        for (int kh = 0; kh < 3; ++kh) {
            float4 a = *(const float4*)(rp + kh * PC);
            float2 b = *(const float2*)(rp + kh * PC + 4);
            const float* wk = wr + kh * 48;
            float4 W0 = *(const float4*)(wk);
            float4 W1 = *(const float4*)(wk + 16);
            float4 W2 = *(const float4*)(wk + 32);
            tap3(a, b, W0.x, W1.x, W2.x, acc0);
            tap3(a, b, W0.y, W1.y, W2.y, acc1);
            tap3(a, b, W0.z, W1.z, W2.z, acc2);
            tap3(a, b, W0.w, W1.w, W2.w, acc3);
        }
    }
    __syncthreads();   // ws reads done before pl overwrites
    const int pbase = pxg * 16 + cog * 4;
    pl4[cic * 112 + pbase + 0] = acc0;
    pl4[cic * 112 + pbase + 1] = acc1;
    pl4[cic * 112 + pbase + 2] = acc2;
    pl4[cic * 112 + pbase + 3] = acc3;
    __syncthreads();

    if (tid < 112) {
        const int rpxg = tid >> 4;
        const int rcog = (tid >> 2) & 3;
        const int j    = tid & 3;
        const int rb   = rpxg * 16 + rcog * 4 + j;
        float4 s = pl4[rb];
        #pragma unroll
        for (int c = 1; c < 16; ++c) {
            float4 t = pl4[c * 112 + rb];
            s.x += t.x; s.y += t.y; s.z += t.z; s.w += t.w;
        }
        const int co = cobase + rcog * 4 + j;
        float inv = g2[co] * rsqrtf(v2[co] + 1e-5f);
        float bb  = b2[co] - m2[co] * inv;
        float4 o;
        o.x = fmaxf(-s.x * inv + bb, 0.f);
        o.y = fmaxf(-s.y * inv + bb, 0.f);
        o.z = fmaxf(-s.z * inv + bb, 0.f);
        o.w = fmaxf(-s.w * inv + bb, 0.f);
        *(float4*)(h3 + (size_t)(n * 64 + co) * 784 + Y * 28 + rpxg * 4) = o;
    }
}

// ---------------- K6: 1x1 adder 64->256 + BN3 + residual + ReLU ----------------
// grid (112, 8): blockIdx.x = n*14 + pxtile(56px). block 448 = 8cog x 14pxg x 4cic.
// Thread: 4px x 4co x 16ci. LDS weights [64][36] UNION partials.
__global__ __launch_bounds__(448) void k6_adder1x1_bn_res_relu(const float* __restrict__ h3,
                                                               const float* __restrict__ w3t,
                                                               const float* __restrict__ x,
                                                               const float* __restrict__ g3,
                                                               const float* __restrict__ b3,
                                                               const float* __restrict__ m3,
                                                               const float* __restrict__ v3,
                                                               float* __restrict__ out) {
    __shared__ __align__(16) float smem[7168];   // ws 2304 floats union pl 7168 floats
    float*  ws  = smem;            // [ci][36] : 32 co + 4 pad
    float4* pl4 = (float4*)smem;   // [cic4][pxg14][cog8][j4] = 1792
    const int tid    = threadIdx.x;
    const int cog    = tid & 7;
    const int pxg    = (tid >> 3) % 14;
    const int cic    = tid / 112;                 // 0..3
    const int n      = blockIdx.x / 14;
    const int p0     = (blockIdx.x % 14) * 56 + pxg * 4;
    const int cobase = blockIdx.y * 32;

    for (int idx = tid; idx < 2048; idx += 448) {
        int ci = idx >> 5, co = idx & 31;
        ws[ci * 36 + co] = w3t[ci * 256 + cobase + co];
    }
    __syncthreads();

    float4 acc0 = {0,0,0,0}, acc1 = acc0, acc2 = acc0, acc3 = acc0;
    const float* hp = h3 + ((size_t)n * 64 + cic * 16) * 784 + p0;
    const float* wp = ws + (cic * 16) * 36 + cog * 4;
    #pragma unroll 8
    for (int i = 0; i < 16; ++i) {
        float4 u = *(const float4*)(hp + (size_t)i * 784);
        float4 w = *(const float4*)(wp + i * 36);
        acc0.x += fabsf(u.x - w.x); acc0.y += fabsf(u.y - w.x); acc0.z += fabsf(u.z - w.x); acc0.w += fabsf(u.w - w.x);
        acc1.x += fabsf(u.x - w.y); acc1.y += fabsf(u.y - w.y); acc1.z += fabsf(u.z - w.y); acc1.w += fabsf(u.w - w.y);
        acc2.x += fabsf(u.x - w.z); acc2.y += fabsf(u.y - w.z); acc2.z += fabsf(u.z - w.z); acc2.w += fabsf(u.w - w.z);
        acc3.x += fabsf(u.x - w.w); acc3.y += fabsf(u.y - w.w); acc3.z += fabsf(u.z - w.w); acc3.w += fabsf(u.w - w.w);
    }
    __syncthreads();   // ws reads done before pl overwrites
    const int pbase = pxg * 32 + cog * 4;
    pl4[cic * 448 + pbase + 0] = acc0;
    pl4[cic * 448 + pbase + 1] = acc1;
    pl4[cic * 448 + pbase + 2] = acc2;
    pl4[cic * 448 + pbase + 3] = acc3;
    __syncthreads();

    {
        const int j = cic;
        float4 s = pl4[pbase + j];
        #pragma unroll
        for (int c = 1; c < 4; ++c) {
            float4 t = pl4[c * 448 + pbase + j];
            s.x += t.x; s.y += t.y; s.z += t.z; s.w += t.w;
        }
        const int co = cobase + cog * 4 + j;
        float inv = g3[co] * rsqrtf(v3[co] + 1e-5f);
        float bb  = b3[co] - m3[co] * inv;
        size_t obase = ((size_t)n * 256 + co) * 784 + p0;
        float4 r = *(const float4*)(x + obase);
        float4 o;
        o.x = fmaxf(-s.x * inv + bb + r.x, 0.f);
        o.y = fmaxf(-s.y * inv + bb + r.y, 0.f);
        o.z = fmaxf(-s.z * inv + bb + r.z, 0.f);
        o.w = fmaxf(-s.w * inv + bb + r.w, 0.f);
        *(float4*)(out + obase) = o;
    }
}

extern "C" void kernel_launch(void* const* d_in, const int* in_sizes, int n_in,
                              void* d_out, int out_size, void* d_ws, size_t ws_size,
                              hipStream_t stream) {
    const float* x  = (const float*)d_in[0];
    const float* w1 = (const float*)d_in[1];
    const float* wp = (const float*)d_in[2];
    const float* w2 = (const float*)d_in[3];
    const float* w3 = (const float*)d_in[4];
    const float* g1 = (const float*)d_in[5];
    const float* b1 = (const float*)d_in[6];
    const float* m1 = (const float*)d_in[7];
    const float* v1 = (const float*)d_in[8];
    const float* g2 = (const float*)d_in[9];
    const float* b2 = (const float*)d_in[10];
    const float* m2 = (const float*)d_in[11];
    const float* v2 = (const float*)d_in[12];
    const float* g3 = (const float*)d_in[13];
    const float* b3 = (const float*)d_in[14];
    const float* m3 = (const float*)d_in[15];
    const float* v3 = (const float*)d_in[16];
    float* out = (float*)d_out;

    float* wsf = (float*)d_ws;
    float* h1p = wsf + OFF_H1P;
    float* h2p = wsf + OFF_H2P;
    float* h3  = wsf + OFF_H3;
    float* w1t = wsf + OFF_W1T;
    float* w2t = wsf + OFF_W2T;
    float* w3t = wsf + OFF_W3T;

    k0_setup<<<dim3(1232), 256, 0, stream>>>((float4*)d_ws, w1, w2, w3, w1t, w2t, w3t);
    k1_adder1x1<<<dim3(224, 4), 448, 0, stream>>>(x, w1t, h1p);
    k2_peg_bn_relu<<<dim3(392), 256, 0, stream>>>(h1p, wp, g1, b1, m1, v1, h2p);
    k3_adder3x3_bn_relu<<<dim3(28, 4, 8), 448, 0, stream>>>(h2p, w2t, g2, b2, m2, v2, h3);
    k6_adder1x1_bn_res_relu<<<dim3(112, 8), 448, 0, stream>>>(h3, w3t, x, g3, b3, m3, v3, out);
}

// Round 11
// 69.806 us; speedup vs baseline: 4.0150x; 1.0018x over previous
//
#include <hip/hip_runtime.h>
#include <math.h>

#define HW 28
#define PR 30            // padded rows
#define PC 32            // padded col stride
#define PPAD (PR * PC)   // 960 floats per padded plane

// ws float offsets
#define OFF_H1P 0
#define OFF_H2P 491520
#define OFF_H3  983040
#define OFF_W2T 1384448   // 36864 floats: [576 r][64 co]  (r = ci*9+tap)
#define OFF_W3T 1421312   // 16384 floats: [64 ci][256 co]
#define OFF_W1T 1437696   // 16384 floats: [256 ci][64 co]

// 4px x 3kw taps for one co
__device__ __forceinline__ void tap3(const float4 a, const float2 b,
                                     const float w0, const float w1, const float w2,
                                     float4& acc) {
    acc.x += fabsf(a.x - w0) + fabsf(a.y - w1) + fabsf(a.z - w2);
    acc.y += fabsf(a.y - w0) + fabsf(a.z - w1) + fabsf(a.w - w2);
    acc.z += fabsf(a.z - w0) + fabsf(a.w - w1) + fabsf(b.x - w2);
    acc.w += fabsf(a.w - w0) + fabsf(b.x - w1) + fabsf(b.y - w2);
}

// ---------------- K0: transpose w1/w2/w3 + zero ONLY the halo cells of h1p/h2p ----------------
// 976 blocks x 256 = 249856 threads, exactly covering:
//   [0,16384)        w1t[ci*64+co]  = w1[co*256+ci]
//   [16384,53248)    w2t[r*64+co]   = w2[co*576+r]
//   [53248,69632)    w3t[ci*256+co] = w3[co*64+ci]
//   [69632,249856)   halo cells: 2 bufs x 512 planes x 176 cells
__global__ __launch_bounds__(256) void k0_setup(const float* __restrict__ w1,
                                                const float* __restrict__ w2,
                                                const float* __restrict__ w3,
                                                float* __restrict__ w1t,
                                                float* __restrict__ w2t,
                                                float* __restrict__ w3t,
                                                float* __restrict__ h1p,
                                                float* __restrict__ h2p) {
    int t = blockIdx.x * 256 + threadIdx.x;
    if (t < 16384) {
        int ci = t >> 6, co = t & 63;
        w1t[t] = w1[co * 256 + ci];
    } else if (t < 53248) {
        int r2 = t - 16384;
        int r = r2 >> 6, co = r2 & 63;
        w2t[r2] = w2[(size_t)co * 576 + r];
    } else if (t < 69632) {
        int r3 = t - 53248;
        int ci = r3 >> 8, co = r3 & 255;
        w3t[r3] = w3[co * 64 + ci];
    } else {
        int h = t - 69632;               // < 180224
        float* buf = (h < 90112) ? h1p : h2p;
        int rem = (h < 90112) ? h : h - 90112;
        int plane = rem / 176, r = rem % 176;
        int row, col;
        if (r < 64) { row = (r >> 5) * 29; col = r & 31; }
        else { int j = r - 64; row = 1 + (j >> 2); int k = j & 3; col = k ? 28 + k : 0; }
        buf[(size_t)plane * PPAD + row * PC + col] = 0.f;
    }
}

// ---------------- K1: 1x1 adder 256->64, out = PADDED h1p (interior only) ----------------
// grid (224, 4): blockIdx.x = n*28 + y. block 448 = 4cog x 7pxg x 16cic.
__global__ __launch_bounds__(448) void k1_adder1x1(const float* __restrict__ x,
                                                   const float* __restrict__ w1t,
                                                   float* __restrict__ h1p) {
    __shared__ __align__(16) float smem[7168];   // ws [256][20] (5120) union pl (7168 floats)
    float*  ws  = smem;
    float4* pl4 = (float4*)smem;
    const int tid    = threadIdx.x;
    const int cog    = tid & 3;
    const int pxg    = (tid >> 2) % 7;
    const int cic    = tid / 28;                 // 0..15
    const int n      = blockIdx.x / 28;
    const int y      = blockIdx.x % 28;
    const int px0    = y * 28 + pxg * 4;
    const int cobase = blockIdx.y * 16;

    for (int idx = tid; idx < 4096; idx += 448) {
        int ci = idx >> 4, co = idx & 15;
        ws[ci * 20 + co] = w1t[ci * 64 + cobase + co];   // coalesced 64B segments
    }
    __syncthreads();

    float4 acc0 = {0,0,0,0}, acc1 = acc0, acc2 = acc0, acc3 = acc0;
    const float* xp = x + ((size_t)n * 256 + cic * 16) * 784 + px0;
    const float* wp = ws + (cic * 16) * 20 + cog * 4;
    #pragma unroll 8
    for (int i = 0; i < 16; ++i) {
        float4 u = *(const float4*)(xp + (size_t)i * 784);
        float4 w = *(const float4*)(wp + i * 20);
        acc0.x += fabsf(u.x - w.x); acc0.y += fabsf(u.y - w.x); acc0.z += fabsf(u.z - w.x); acc0.w += fabsf(u.w - w.x);
        acc1.x += fabsf(u.x - w.y); acc1.y += fabsf(u.y - w.y); acc1.z += fabsf(u.z - w.y); acc1.w += fabsf(u.w - w.y);
        acc2.x += fabsf(u.x - w.z); acc2.y += fabsf(u.y - w.z); acc2.z += fabsf(u.z - w.z); acc2.w += fabsf(u.w - w.z);
        acc3.x += fabsf(u.x - w.w); acc3.y += fabsf(u.y - w.w); acc3.z += fabsf(u.z - w.w); acc3.w += fabsf(u.w - w.w);
    }
    __syncthreads();   // all ws reads done before pl overwrites the union
    const int pbase = pxg * 16 + cog * 4;
    pl4[cic * 112 + pbase + 0] = acc0;
    pl4[cic * 112 + pbase + 1] = acc1;
    pl4[cic * 112 + pbase + 2] = acc2;
    pl4[cic * 112 + pbase + 3] = acc3;
    __syncthreads();

    if (tid < 112) {
        const int rpxg = tid >> 4;
        const int rcog = (tid >> 2) & 3;
        const int j    = tid & 3;
        const int rb   = rpxg * 16 + rcog * 4 + j;
        float4 s = pl4[rb];
        #pragma unroll
        for (int c = 1; c < 16; ++c) {
            float4 t = pl4[c * 112 + rb];
            s.x += t.x; s.y += t.y; s.z += t.z; s.w += t.w;
        }
        const int co = cobase + rcog * 4 + j;
        float* op = h1p + ((size_t)(n * 64 + co) * PR + y + 1) * PC + rpxg * 4 + 1;
        op[0] = -s.x; op[1] = -s.y; op[2] = -s.z; op[3] = -s.w;
    }
}

// ---------------- K2: depthwise 3x3 (PEG) + BN1 + ReLU, padded->padded ----------------
__global__ __launch_bounds__(256) void k2_peg_bn_relu(const float* __restrict__ h1p,
                                                      const float* __restrict__ wp,
                                                      const float* __restrict__ g1,
                                                      const float* __restrict__ b1,
                                                      const float* __restrict__ m1,
                                                      const float* __restrict__ v1,
                                                      float* __restrict__ h2p) {
    const int t   = blockIdx.x * 256 + threadIdx.x;   // < 8*64*196
    const int pxq = t % 196;
    const int c   = (t / 196) & 63;
    const int n   = t / (196 * 64);
    const int p0  = pxq * 4;
    const int y   = p0 / 28, xx = p0 % 28;

    const float* base = h1p + ((size_t)(n * 64 + c) * PR + y) * PC + xx;
    const float* wc   = wp + c * 9;
    float4 acc = {0,0,0,0};
    #pragma unroll
    for (int kh = 0; kh < 3; ++kh) {
        float4 a = *(const float4*)(base + kh * PC);
        float2 b = *(const float2*)(base + kh * PC + 4);
        tap3(a, b, wc[kh * 3 + 0], wc[kh * 3 + 1], wc[kh * 3 + 2], acc);
    }
    float inv = g1[c] * rsqrtf(v1[c] + 1e-5f);
    float bb  = b1[c] - m1[c] * inv;
    float* op = h2p + ((size_t)(n * 64 + c) * PR + y + 1) * PC + xx + 1;
    op[0] = fmaxf(-acc.x * inv + bb, 0.f);
    op[1] = fmaxf(-acc.y * inv + bb, 0.f);
    op[2] = fmaxf(-acc.z * inv + bb, 0.f);
    op[3] = fmaxf(-acc.w * inv + bb, 0.f);
}

// ---------------- K3: 3x3 adder 64->64 + BN2 + ReLU ----------------
// grid (28, 4, 8): one output row per block. block 448 = 4cog x 7pxg x 16cic.
__global__ __launch_bounds__(448) void k3_adder3x3_bn_relu(const float* __restrict__ h2p,
                                                           const float* __restrict__ w2t,
                                                           const float* __restrict__ g2,
                                                           const float* __restrict__ b2,
                                                           const float* __restrict__ m2,
                                                           const float* __restrict__ v2,
                                                           float* __restrict__ h3) {
    __shared__ __align__(16) float smem[9216];   // ws [576 r][16 co] (36KB) union pl (28KB)
    float*  ws  = smem;
    float4* pl4 = (float4*)smem;
    const int tid    = threadIdx.x;
    const int cog    = tid & 3;
    const int pxg    = (tid >> 2) % 7;
    const int cic    = tid / 28;                  // 0..15
    const int Y      = blockIdx.x;                // output row 0..27
    const int cobase = blockIdx.y * 16;
    const int n      = blockIdx.z;
    const int xx0    = pxg * 4;

    #pragma unroll
    for (int k = 0; k < 21; ++k) {
        int idx = tid + k * 448;
        if (idx < 9216) ws[idx] = w2t[(size_t)(idx >> 4) * 64 + cobase + (idx & 15)];
    }
    __syncthreads();

    float4 acc0 = {0,0,0,0}, acc1 = acc0, acc2 = acc0, acc3 = acc0;
    #pragma unroll 2
    for (int i = 0; i < 4; ++i) {
        const int ci = cic * 4 + i;
        const float* rp = h2p + (((size_t)(n * 64 + ci)) * PR + Y) * PC + xx0;
        const float* wr = ws + ci * 144 + cog * 4;   // 9 taps * 16
        #pragma unroll
        for (int kh = 0; kh < 3; ++kh) {
            float4 a = *(const float4*)(rp + kh * PC);
            float2 b = *(const float2*)(rp + kh * PC + 4);
            const float* wk = wr + kh * 48;
            float4 W0 = *(const float4*)(wk);
            float4 W1 = *(const float4*)(wk + 16);
            float4 W2 = *(const float4*)(wk + 32);
            tap3(a, b, W0.x, W1.x, W2.x, acc0);
            tap3(a, b, W0.y, W1.y, W2.y, acc1);
            tap3(a, b, W0.z, W1.z, W2.z, acc2);
            tap3(a, b, W0.w, W1.w, W2.w, acc3);
        }
    }
    __syncthreads();   // ws reads done before pl overwrites
    const int pbase = pxg * 16 + cog * 4;
    pl4[cic * 112 + pbase + 0] = acc0;
    pl4[cic * 112 + pbase + 1] = acc1;
    pl4[cic * 112 + pbase + 2] = acc2;
    pl4[cic * 112 + pbase + 3] = acc3;
    __syncthreads();

    if (tid < 112) {
        const int rpxg = tid >> 4;
        const int rcog = (tid >> 2) & 3;
        const int j    = tid & 3;
        const int rb   = rpxg * 16 + rcog * 4 + j;
        float4 s = pl4[rb];
        #pragma unroll
        for (int c = 1; c < 16; ++c) {
            float4 t = pl4[c * 112 + rb];
            s.x += t.x; s.y += t.y; s.z += t.z; s.w += t.w;
        }
        const int co = cobase + rcog * 4 + j;
        float inv = g2[co] * rsqrtf(v2[co] + 1e-5f);
        float bb  = b2[co] - m2[co] * inv;
        float4 o;
        o.x = fmaxf(-s.x * inv + bb, 0.f);
        o.y = fmaxf(-s.y * inv + bb, 0.f);
        o.z = fmaxf(-s.z * inv + bb, 0.f);
        o.w = fmaxf(-s.w * inv + bb, 0.f);
        *(float4*)(h3 + (size_t)(n * 64 + co) * 784 + Y * 28 + rpxg * 4) = o;
    }
}

// ---------------- K6: 1x1 adder 64->256 + BN3 + residual + ReLU ----------------
// grid (112, 8): blockIdx.x = n*14 + pxtile(56px). block 448 = 8cog x 14pxg x 4cic.
__global__ __launch_bounds__(448) void k6_adder1x1_bn_res_relu(const float* __restrict__ h3,
                                                               const float* __restrict__ w3t,
                                                               const float* __restrict__ x,
                                                               const float* __restrict__ g3,
                                                               const float* __restrict__ b3,
                                                               const float* __restrict__ m3,
                                                               const float* __restrict__ v3,
                                                               float* __restrict__ out) {
    __shared__ __align__(16) float smem[7168];   // ws 2304 floats union pl 7168 floats
    float*  ws  = smem;            // [ci][36] : 32 co + 4 pad
    float4* pl4 = (float4*)smem;   // [cic4][pxg14][cog8][j4] = 1792
    const int tid    = threadIdx.x;
    const int cog    = tid & 7;
    const int pxg    = (tid >> 3) % 14;
    const int cic    = tid / 112;                 // 0..3
    const int n      = blockIdx.x / 14;
    const int p0     = (blockIdx.x % 14) * 56 + pxg * 4;
    const int cobase = blockIdx.y * 32;

    for (int idx = tid; idx < 2048; idx += 448) {
        int ci = idx >> 5, co = idx & 31;
        ws[ci * 36 + co] = w3t[ci * 256 + cobase + co];
    }
    __syncthreads();

    float4 acc0 = {0,0,0,0}, acc1 = acc0, acc2 = acc0, acc3 = acc0;
    const float* hp = h3 + ((size_t)n * 64 + cic * 16) * 784 + p0;
    const float* wp = ws + (cic * 16) * 36 + cog * 4;
    #pragma unroll 8
    for (int i = 0; i < 16; ++i) {
        float4 u = *(const float4*)(hp + (size_t)i * 784);
        float4 w = *(const float4*)(wp + i * 36);
        acc0.x += fabsf(u.x - w.x); acc0.y += fabsf(u.y - w.x); acc0.z += fabsf(u.z - w.x); acc0.w += fabsf(u.w - w.x);
        acc1.x += fabsf(u.x - w.y); acc1.y += fabsf(u.y - w.y); acc1.z += fabsf(u.z - w.y); acc1.w += fabsf(u.w - w.y);
        acc2.x += fabsf(u.x - w.z); acc2.y += fabsf(u.y - w.z); acc2.z += fabsf(u.z - w.z); acc2.w += fabsf(u.w - w.z);
        acc3.x += fabsf(u.x - w.w); acc3.y += fabsf(u.y - w.w); acc3.z += fabsf(u.z - w.w); acc3.w += fabsf(u.w - w.w);
    }
    __syncthreads();   // ws reads done before pl overwrites
    const int pbase = pxg * 32 + cog * 4;
    pl4[cic * 448 + pbase + 0] = acc0;
    pl4[cic * 448 + pbase + 1] = acc1;
    pl4[cic * 448 + pbase + 2] = acc2;
    pl4[cic * 448 + pbase + 3] = acc3;
    __syncthreads();

    {
        const int j = cic;
        float4 s = pl4[pbase + j];
        #pragma unroll
        for (int c = 1; c < 4; ++c) {
            float4 t = pl4[c * 448 + pbase + j];
            s.x += t.x; s.y += t.y; s.z += t.z; s.w += t.w;
        }
        const int co = cobase + cog * 4 + j;
        float inv = g3[co] * rsqrtf(v3[co] + 1e-5f);
        float bb  = b3[co] - m3[co] * inv;
        size_t obase = ((size_t)n * 256 + co) * 784 + p0;
        float4 r = *(const float4*)(x + obase);
        float4 o;
        o.x = fmaxf(-s.x * inv + bb + r.x, 0.f);
        o.y = fmaxf(-s.y * inv + bb + r.y, 0.f);
        o.z = fmaxf(-s.z * inv + bb + r.z, 0.f);
        o.w = fmaxf(-s.w * inv + bb + r.w, 0.f);
        *(float4*)(out + obase) = o;
    }
}

extern "C" void kernel_launch(void* const* d_in, const int* in_sizes, int n_in,
                              void* d_out, int out_size, void* d_ws, size_t ws_size,
                              hipStream_t stream) {
    const float* x  = (const float*)d_in[0];
    const float* w1 = (const float*)d_in[1];
    const float* wp = (const float*)d_in[2];
    const float* w2 = (const float*)d_in[3];
    const float* w3 = (const float*)d_in[4];
    const float* g1 = (const float*)d_in[5];
    const float* b1 = (const float*)d_in[6];
    const float* m1 = (const float*)d_in[7];
    const float* v1 = (const float*)d_in[8];
    const float* g2 = (const float*)d_in[9];
    const float* b2 = (const float*)d_in[10];
    const float* m2 = (const float*)d_in[11];
    const float* v2 = (const float*)d_in[12];
    const float* g3 = (const float*)d_in[13];
    const float* b3 = (const float*)d_in[14];
    const float* m3 = (const float*)d_in[15];
    const float* v3 = (const float*)d_in[16];
    float* out = (float*)d_out;

    float* wsf = (float*)d_ws;
    float* h1p = wsf + OFF_H1P;
    float* h2p = wsf + OFF_H2P;
    float* h3  = wsf + OFF_H3;
    float* w2t = wsf + OFF_W2T;
    float* w3t = wsf + OFF_W3T;
    float* w1t = wsf + OFF_W1T;

    k0_setup<<<dim3(976), 256, 0, stream>>>(w1, w2, w3, w1t, w2t, w3t, h1p, h2p);
    k1_adder1x1<<<dim3(224, 4), 448, 0, stream>>>(x, w1t, h1p);
    k2_peg_bn_relu<<<dim3(392), 256, 0, stream>>>(h1p, wp, g1, b1, m1, v1, h2p);
    k3_adder3x3_bn_relu<<<dim3(28, 4, 8), 448, 0, stream>>>(h2p, w2t, g2, b2, m2, v2, h3);
    k6_adder1x1_bn_res_relu<<<dim3(112, 8), 448, 0, stream>>>(h3, w3t, x, g3, b3, m3, v3, out);
}

// Round 12
// 66.807 us; speedup vs baseline: 4.1952x; 1.0449x over previous
//
#include <hip/hip_runtime.h>
#include <math.h>

#define HW 28
#define PR 30            // padded rows
#define PC 32            // padded col stride
#define PPAD (PR * PC)   // 960 floats per padded plane

// ws float offsets
#define OFF_H1P 0
#define OFF_H2P 491520
#define OFF_H3  983040

// 4px x 3kw taps for one co
__device__ __forceinline__ void tap3(const float4 a, const float2 b,
                                     const float w0, const float w1, const float w2,
                                     float4& acc) {
    acc.x += fabsf(a.x - w0) + fabsf(a.y - w1) + fabsf(a.z - w2);
    acc.y += fabsf(a.y - w0) + fabsf(a.z - w1) + fabsf(a.w - w2);
    acc.z += fabsf(a.z - w0) + fabsf(a.w - w1) + fabsf(b.x - w2);
    acc.w += fabsf(a.w - w0) + fabsf(b.x - w1) + fabsf(b.y - w2);
}

// ---------------- K1: 1x1 adder 256->64 -> PADDED h1p, halos folded in ----------------
// grid (224, 4): blockIdx.x = n*28 + y. block 448 = 4cog x 7pxg x 16cic.
__global__ __launch_bounds__(448) void k1_adder1x1(const float* __restrict__ x,
                                                   const float* __restrict__ w1,
                                                   float* __restrict__ h1p) {
    __shared__ __align__(16) float smem[7168];   // ws [256][20] (5120) union pl (7168)
    float*  ws  = smem;
    float4* pl4 = (float4*)smem;
    const int tid    = threadIdx.x;
    const int cog    = tid & 3;
    const int pxg    = (tid >> 2) % 7;
    const int cic    = tid / 28;                 // 0..15
    const int n      = blockIdx.x / 28;
    const int y      = blockIdx.x % 28;
    const int px0    = y * 28 + pxg * 4;
    const int cobase = blockIdx.y * 16;

    for (int idx = tid; idx < 4096; idx += 448) {
        int co = idx >> 8, ci = idx & 255;       // co-major: coalesced w1 reads
        ws[ci * 20 + co] = w1[(size_t)(cobase + co) * 256 + ci];
    }
    __syncthreads();

    float4 acc0 = {0,0,0,0}, acc1 = acc0, acc2 = acc0, acc3 = acc0;
    const float* xp = x + ((size_t)n * 256 + cic * 16) * 784 + px0;
    const float* wp = ws + (cic * 16) * 20 + cog * 4;
    #pragma unroll 8
    for (int i = 0; i < 16; ++i) {
        float4 u = *(const float4*)(xp + (size_t)i * 784);
        float4 w = *(const float4*)(wp + i * 20);
        acc0.x += fabsf(u.x - w.x); acc0.y += fabsf(u.y - w.x); acc0.z += fabsf(u.z - w.x); acc0.w += fabsf(u.w - w.x);
        acc1.x += fabsf(u.x - w.y); acc1.y += fabsf(u.y - w.y); acc1.z += fabsf(u.z - w.y); acc1.w += fabsf(u.w - w.y);
        acc2.x += fabsf(u.x - w.z); acc2.y += fabsf(u.y - w.z); acc2.z += fabsf(u.z - w.z); acc2.w += fabsf(u.w - w.z);
        acc3.x += fabsf(u.x - w.w); acc3.y += fabsf(u.y - w.w); acc3.z += fabsf(u.z - w.w); acc3.w += fabsf(u.w - w.w);
    }
    __syncthreads();   // all ws reads done before pl overwrites the union
    const int pbase = pxg * 16 + cog * 4;
    pl4[cic * 112 + pbase + 0] = acc0;
    pl4[cic * 112 + pbase + 1] = acc1;
    pl4[cic * 112 + pbase + 2] = acc2;
    pl4[cic * 112 + pbase + 3] = acc3;
    __syncthreads();

    if (tid < 112) {
        const int rpxg = tid >> 4;
        const int rcog = (tid >> 2) & 3;
        const int j    = tid & 3;
        const int rb   = rpxg * 16 + rcog * 4 + j;
        float4 s = pl4[rb];
        #pragma unroll
        for (int c = 1; c < 16; ++c) {
            float4 t = pl4[c * 112 + rb];
            s.x += t.x; s.y += t.y; s.z += t.z; s.w += t.w;
        }
        const int co = cobase + rcog * 4 + j;
        float* op = h1p + ((size_t)(n * 64 + co) * PR + y + 1) * PC + rpxg * 4 + 1;
        op[0] = -s.x; op[1] = -s.y; op[2] = -s.z; op[3] = -s.w;
        if (rpxg == 0) op[-1] = 0.f;                               // col 0 halo
        if (rpxg == 6) { op[4] = 0.f; op[5] = 0.f; op[6] = 0.f; }  // cols 29..31
    }
    if (y == 0 || y == 27) {                     // padded rows 0 / 29 halo (16 cos)
        const int prow = (y == 0) ? 0 : 29;
        for (int idx = tid; idx < 512; idx += 448) {
            int coi = idx >> 5, col = idx & 31;
            h1p[((size_t)(n * 64 + cobase + coi) * PR + prow) * PC + col] = 0.f;
        }
    }
}

// ---------------- K2: depthwise 3x3 (PEG) + BN1 + ReLU -> PADDED h2p (+ halo) ----------------
// grid 744 x 256 = 190464 threads: [0,100352) interior, [100352,190464) halo zeros.
__global__ __launch_bounds__(256) void k2_peg_bn_relu(const float* __restrict__ h1p,
                                                      const float* __restrict__ wp,
                                                      const float* __restrict__ g1,
                                                      const float* __restrict__ b1,
                                                      const float* __restrict__ m1,
                                                      const float* __restrict__ v1,
                                                      float* __restrict__ h2p) {
    const int t = blockIdx.x * 256 + threadIdx.x;
    if (t < 100352) {
        const int pxq = t % 196;
        const int c   = (t / 196) & 63;
        const int n   = t / (196 * 64);
        const int p0  = pxq * 4;
        const int y   = p0 / 28, xx = p0 % 28;
        const float* base = h1p + ((size_t)(n * 64 + c) * PR + y) * PC + xx;
        const float* wc   = wp + c * 9;
        float4 acc = {0,0,0,0};
        #pragma unroll
        for (int kh = 0; kh < 3; ++kh) {
            float4 a = *(const float4*)(base + kh * PC);
            float2 b = *(const float2*)(base + kh * PC + 4);
            tap3(a, b, wc[kh * 3 + 0], wc[kh * 3 + 1], wc[kh * 3 + 2], acc);
        }
        float inv = g1[c] * rsqrtf(v1[c] + 1e-5f);
        float bb  = b1[c] - m1[c] * inv;
        float* op = h2p + ((size_t)(n * 64 + c) * PR + y + 1) * PC + xx + 1;
        op[0] = fmaxf(-acc.x * inv + bb, 0.f);
        op[1] = fmaxf(-acc.y * inv + bb, 0.f);
        op[2] = fmaxf(-acc.z * inv + bb, 0.f);
        op[3] = fmaxf(-acc.w * inv + bb, 0.f);
    } else {                                     // 512 planes x 176 halo cells of h2p
        int i = t - 100352;
        int plane = i / 176, r = i % 176;
        int row, col;
        if (r < 64) { row = (r >> 5) * 29; col = r & 31; }
        else { int j = r - 64; row = 1 + (j >> 2); int k = j & 3; col = k ? 28 + k : 0; }
        h2p[(size_t)plane * PPAD + row * PC + col] = 0.f;
    }
}

// ---------------- K3: 3x3 adder 64->64 + BN2 + ReLU ----------------
// grid (14, 4, 8): 2 output rows per block. block 448 = 4cog x 14pxg(2x7) x 8cic.
// Weights gather-staged from w2 (co-major, coalesced), stride-20 LDS, union with pl.
__global__ __launch_bounds__(448) void k3_adder3x3_bn_relu(const float* __restrict__ h2p,
                                                           const float* __restrict__ w2,
                                                           const float* __restrict__ g2,
                                                           const float* __restrict__ b2,
                                                           const float* __restrict__ m2,
                                                           const float* __restrict__ v2,
                                                           float* __restrict__ h3) {
    __shared__ __align__(16) float smem[11520];  // ws [576 r][20] (46KB) union pl (28KB)
    float*  ws  = smem;
    float4* pl4 = (float4*)smem;
    const int tid    = threadIdx.x;
    const int cog    = tid & 3;
    const int pxg    = (tid >> 2) % 14;
    const int cic    = tid / 56;                  // 0..7
    const int y0     = blockIdx.x * 2;
    const int cobase = blockIdx.y * 16;
    const int n      = blockIdx.z;
    const int yl     = pxg / 7;                   // 0..1
    const int xx0    = (pxg % 7) * 4;
    const int Y      = y0 + yl;                   // output row

    for (int idx = tid; idx < 9216; idx += 448) {
        int co = idx / 576;                       // co-major: coalesced w2 reads
        int r  = idx - co * 576;                  // r = ci*9 + tap
        ws[r * 20 + co] = w2[(size_t)(cobase + co) * 576 + r];
    }
    __syncthreads();

    float4 acc0 = {0,0,0,0}, acc1 = acc0, acc2 = acc0, acc3 = acc0;
    #pragma unroll 2
    for (int i = 0; i < 8; ++i) {
        const int ci = cic * 8 + i;
        const float* rp = h2p + (((size_t)(n * 64 + ci)) * PR + Y) * PC + xx0;
        const float* wr = ws + ci * 180 + cog * 4;   // 9 taps * 20
        #pragma unroll
        for (int kh = 0; kh < 3; ++kh) {
            float4 a = *(const float4*)(rp + kh * PC);
            float2 b = *(const float2*)(rp + kh * PC + 4);
            const float* wk = wr + kh * 60;
            float4 W0 = *(const float4*)(wk);
            float4 W1 = *(const float4*)(wk + 20);
            float4 W2 = *(const float4*)(wk + 40);
            tap3(a, b, W0.x, W1.x, W2.x, acc0);
            tap3(a, b, W0.y, W1.y, W2.y, acc1);
            tap3(a, b, W0.z, W1.z, W2.z, acc2);
            tap3(a, b, W0.w, W1.w, W2.w, acc3);
        }
    }
    __syncthreads();   // ws reads done before pl overwrites
    const int pbase = pxg * 16 + cog * 4;
    pl4[cic * 224 + pbase + 0] = acc0;
    pl4[cic * 224 + pbase + 1] = acc1;
    pl4[cic * 224 + pbase + 2] = acc2;
    pl4[cic * 224 + pbase + 3] = acc3;
    __syncthreads();

    if (tid < 224) {
        const int j = cic;                        // 0..3 for tid<224
        float4 s = pl4[pbase + j];
        #pragma unroll
        for (int c = 1; c < 8; ++c) {
            float4 t = pl4[c * 224 + pbase + j];
            s.x += t.x; s.y += t.y; s.z += t.z; s.w += t.w;
        }
        const int co = cobase + cog * 4 + j;
        float inv = g2[co] * rsqrtf(v2[co] + 1e-5f);
        float bb  = b2[co] - m2[co] * inv;
        float4 o;
        o.x = fmaxf(-s.x * inv + bb, 0.f);
        o.y = fmaxf(-s.y * inv + bb, 0.f);
        o.z = fmaxf(-s.z * inv + bb, 0.f);
        o.w = fmaxf(-s.w * inv + bb, 0.f);
        *(float4*)(h3 + (size_t)(n * 64 + co) * 784 + Y * 28 + xx0) = o;
    }
}

// ---------------- K6: 1x1 adder 64->256 + BN3 + residual + ReLU ----------------
// grid (112, 8): blockIdx.x = n*14 + pxtile(56px). block 448 = 8cog x 14pxg x 4cic.
__global__ __launch_bounds__(448) void k6_adder1x1_bn_res_relu(const float* __restrict__ h3,
                                                               const float* __restrict__ w3,
                                                               const float* __restrict__ x,
                                                               const float* __restrict__ g3,
                                                               const float* __restrict__ b3,
                                                               const float* __restrict__ m3,
                                                               const float* __restrict__ v3,
                                                               float* __restrict__ out) {
    __shared__ __align__(16) float smem[7168];   // ws [64][36] (2304) union pl (7168)
    float*  ws  = smem;
    float4* pl4 = (float4*)smem;
    const int tid    = threadIdx.x;
    const int cog    = tid & 7;
    const int pxg    = (tid >> 3) % 14;
    const int cic    = tid / 112;                 // 0..3
    const int n      = blockIdx.x / 14;
    const int p0     = (blockIdx.x % 14) * 56 + pxg * 4;
    const int cobase = blockIdx.y * 32;

    for (int idx = tid; idx < 2048; idx += 448) {
        int co = idx >> 6, ci = idx & 63;        // co-major: coalesced w3 reads
        ws[ci * 36 + co] = w3[(size_t)(cobase + co) * 64 + ci];
    }
    __syncthreads();

    float4 acc0 = {0,0,0,0}, acc1 = acc0, acc2 = acc0, acc3 = acc0;
    const float* hp = h3 + ((size_t)n * 64 + cic * 16) * 784 + p0;
    const float* wp = ws + (cic * 16) * 36 + cog * 4;
    #pragma unroll 8
    for (int i = 0; i < 16; ++i) {
        float4 u = *(const float4*)(hp + (size_t)i * 784);
        float4 w = *(const float4*)(wp + i * 36);
        acc0.x += fabsf(u.x - w.x); acc0.y += fabsf(u.y - w.x); acc0.z += fabsf(u.z - w.x); acc0.w += fabsf(u.w - w.x);
        acc1.x += fabsf(u.x - w.y); acc1.y += fabsf(u.y - w.y); acc1.z += fabsf(u.z - w.y); acc1.w += fabsf(u.w - w.y);
        acc2.x += fabsf(u.x - w.z); acc2.y += fabsf(u.y - w.z); acc2.z += fabsf(u.z - w.z); acc2.w += fabsf(u.w - w.z);
        acc3.x += fabsf(u.x - w.w); acc3.y += fabsf(u.y - w.w); acc3.z += fabsf(u.z - w.w); acc3.w += fabsf(u.w - w.w);
    }
    __syncthreads();   // ws reads done before pl overwrites
    const int pbase = pxg * 32 + cog * 4;
    pl4[cic * 448 + pbase + 0] = acc0;
    pl4[cic * 448 + pbase + 1] = acc1;
    pl4[cic * 448 + pbase + 2] = acc2;
    pl4[cic * 448 + pbase + 3] = acc3;
    __syncthreads();

    {
        const int j = cic;
        float4 s = pl4[pbase + j];
        #pragma unroll
        for (int c = 1; c < 4; ++c) {
            float4 t = pl4[c * 448 + pbase + j];
            s.x += t.x; s.y += t.y; s.z += t.z; s.w += t.w;
        }
        const int co = cobase + cog * 4 + j;
        float inv = g3[co] * rsqrtf(v3[co] + 1e-5f);
        float bb  = b3[co] - m3[co] * inv;
        size_t obase = ((size_t)n * 256 + co) * 784 + p0;
        float4 r = *(const float4*)(x + obase);
        float4 o;
        o.x = fmaxf(-s.x * inv + bb + r.x, 0.f);
        o.y = fmaxf(-s.y * inv + bb + r.y, 0.f);
        o.z = fmaxf(-s.z * inv + bb + r.z, 0.f);
        o.w = fmaxf(-s.w * inv + bb + r.w, 0.f);
        *(float4*)(out + obase) = o;
    }
}

extern "C" void kernel_launch(void* const* d_in, const int* in_sizes, int n_in,
                              void* d_out, int out_size, void* d_ws, size_t ws_size,
                              hipStream_t stream) {
    const float* x  = (const float*)d_in[0];
    const float* w1 = (const float*)d_in[1];
    const float* wp = (const float*)d_in[2];
    const float* w2 = (const float*)d_in[3];
    const float* w3 = (const float*)d_in[4];
    const float* g1 = (const float*)d_in[5];
    const float* b1 = (const float*)d_in[6];
    const float* m1 = (const float*)d_in[7];
    const float* v1 = (const float*)d_in[8];
    const float* g2 = (const float*)d_in[9];
    const float* b2 = (const float*)d_in[10];
    const float* m2 = (const float*)d_in[11];
    const float* v2 = (const float*)d_in[12];
    const float* g3 = (const float*)d_in[13];
    const float* b3 = (const float*)d_in[14];
    const float* m3 = (const float*)d_in[15];
    const float* v3 = (const float*)d_in[16];
    float* out = (float*)d_out;

    float* wsf = (float*)d_ws;
    float* h1p = wsf + OFF_H1P;
    float* h2p = wsf + OFF_H2P;
    float* h3  = wsf + OFF_H3;

    k1_adder1x1<<<dim3(224, 4), 448, 0, stream>>>(x, w1, h1p);
    k2_peg_bn_relu<<<dim3(744), 256, 0, stream>>>(h1p, wp, g1, b1, m1, v1, h2p);
    k3_adder3x3_bn_relu<<<dim3(14, 4, 8), 448, 0, stream>>>(h2p, w2, g2, b2, m2, v2, h3);
    k6_adder1x1_bn_res_relu<<<dim3(112, 8), 448, 0, stream>>>(h3, w3, x, g3, b3, m3, v3, out);
}